// Round 18
// baseline (459.908 us; speedup 1.0000x reference)
//
#include <hip/hip_runtime.h>

// Per-sample depthwise 7x7 cross-correlation, NHWC, SAME padding.
// inputs:  [B,H,W,C] fp32, kernels: [B,7,7,C] fp32, out: [B,H,W,C] fp32.
// out[b,y,x,c] = sum_{i,j} in[b, y+i-3, x+j-3, c] * ker[b,i,j,c]  (zero pad)
//
// R18: c-PAIR layout + depth-2 prefetch in the 128-VGPR tier.
// Thread = (4 x-outputs) x (2 adjacent channels): each tap is ONE float2 load
// (10 VMEM/pass vs R16's 14), packs with ONE cvt_pkrtz (10 vs 13), weights
// packed per c-pair in LDS (no broadcast), stores are 4 dwordx2. pk_fma does
// (c0,c1) per lane; 196 pk_fma per 8 outputs, same as R16.
// KEY: grid = 262144 threads = 16 waves/CU = 4 waves/SIMD -> full residency
// needs only the 128-reg tier. __launch_bounds__(256,4) caps VGPR at 128,
// making depth-2 A/B tap prefetch (R12's scheme) affordable WITHOUT the
// occupancy cliff that killed it at the 64-reg tier.

#define BB 32
#define HH 128
#define WW 128
#define CC 128
#define KH 7
#define KW 7

#define XPT 4                        // x outputs per thread
#define NTAP (XPT + KW - 1)          // 10 tap columns per thread
#define XG 4                         // x-groups (waves) per 256-thr block
#define SLABW (XG * XPT)             // 16 output columns per block
#define NXS (WW / SLABW)             // 8 x-slabs
#define YSPLIT 4
#define YROWS (HH / YSPLIT)          // 32 output rows per block
#define GRID (BB * NXS * YSPLIT)     // 1024 blocks = 4/CU, 16 waves/CU
#define WSTRIDE 52                   // per-c-pair weight uints (49 + pad)
#define NPASS (YROWS + KH - 1)       // 38 passes = 19 A/B pairs

typedef _Float16 half2_t __attribute__((ext_vector_type(2)));

static __device__ __forceinline__ half2_t pk(float a, float b) {
#if __has_builtin(__builtin_amdgcn_cvt_pkrtz)
    return __builtin_bit_cast(half2_t, __builtin_amdgcn_cvt_pkrtz(a, b));
#else
    half2_t r; r.x = (_Float16)a; r.y = (_Float16)b; return r;
#endif
}

static __device__ __forceinline__ half2_t bc(unsigned u) {
    return __builtin_bit_cast(half2_t, u);
}

__global__ __launch_bounds__(256, 4) void crossconv_kernel(
    const float* __restrict__ in,
    const float* __restrict__ ker,
    float* __restrict__ out)
{
    __shared__ unsigned lds_w[64 * WSTRIDE];   // 13312 B

    const int tid  = threadIdx.x;
    const int lane = tid & 63;        // c-pair index; c0 = 2*lane
    const int c0   = lane * 2;
    const int xg   = __builtin_amdgcn_readfirstlane(tid >> 6);  // 0..3, per-wave

    // Bijective XCD swizzle (GRID=1024, 128 blocks/XCD = 4 whole samples).
    const int bid = blockIdx.x;
    const int swz = (bid & 7) * (GRID / 8) + (bid >> 3);
    const int b  = swz >> 5;          // 32 blocks per sample (8 xs x 4 yh)
    const int xs = (swz >> 2) & 7;
    const int yh = swz & 3;
    const int x0 = xs * SLABW + xg * XPT;   // wave-uniform
    const int y0 = yh * YROWS;

    // Stage per-c-pair packed weights: lds_w[pair][f] = (w_f[c0], w_f[c0+1]).
    {
        const float* kb = ker + ((size_t)b * KH * KW) * CC + c0;
        for (int f = xg; f < KH * KW; f += XG) {
            const float2 kv = *(const float2*)(kb + (size_t)f * CC);
            lds_w[lane * WSTRIDE + f] = __builtin_bit_cast(unsigned, pk(kv.x, kv.y));
        }
    }
    __syncthreads();

    const float* ib = in  + ((size_t)b * HH * WW) * CC;
    float*       ob = out + ((size_t)b * HH * WW) * CC;
    const unsigned* wp = &lds_w[lane * WSTRIDE];

    const bool interior = (x0 >= 3) && (x0 + 6 < WW);

    // Issue the 10 float2 tap loads for row yi (consumed ~2 passes later).
    // Base rebased to col x0+2: offsets (j-5)*512 B in [-2560,2048], 13-bit imm.
    auto issue_taps = [&](float2* t, int yi) {
        if (yi < 0 || yi >= HH) {
            #pragma unroll
            for (int j = 0; j < NTAP; ++j) t[j] = float2{0.0f, 0.0f};
            return;
        }
        const float* base = ib + (size_t)yi * WW * CC + (x0 + 2) * CC + c0;
        if (interior) {
            #pragma unroll
            for (int j = 0; j < NTAP; ++j)
                t[j] = *(const float2*)(base + (j - 5) * CC);
        } else {
            #pragma unroll
            for (int j = 0; j < NTAP; ++j) {
                const int xx = x0 - 3 + j;
                t[j] = (xx >= 0 && xx < WW) ? *(const float2*)(base + (j - 5) * CC)
                                            : float2{0.0f, 0.0f};
            }
        }
    };

    // Sliding ring: acc[s][xo] = half2 (c0,c1) partials for output row yi-3+s.
    half2_t acc[KH][XPT];
    #pragma unroll
    for (int s = 0; s < KH; ++s)
        #pragma unroll
        for (int xo = 0; xo < XPT; ++xo) acc[s][xo] = half2_t{0, 0};

    const int yi0 = y0 - 3;

    // Packed current-row taps: p[j] = (t[j].c0, t[j].c1). Output xo uses p[xo+j].
    half2_t p[NTAP];
    float2 tA[NTAP], tB[NTAP];

    issue_taps(tA, yi0);
    #pragma unroll
    for (int j = 0; j < NTAP; ++j) p[j] = pk(tA[j].x, tA[j].y);
    issue_taps(tB, yi0 + 1);

    // One pass: dots for input row yi on p, store completed output row,
    // ring shift, then pack NEXT row from tsrc (vmcnt wait lands there).
    auto pass = [&](int yi, const float2* tsrc) {
        // Prevent LICM of the 49 weight quads (would need +49 regs -> spill).
        asm volatile("" ::: "memory");

        #pragma unroll
        for (int k = 0; k < 12; ++k) {
            const uint4 wq = *(const uint4*)(wp + k * 4);
            #pragma unroll
            for (int m = 0; m < 4; ++m) {
                const int f = k * 4 + m;
                const int i = f / KW, j = f % KW;
                const int s = 6 - i;
                const half2_t wv = bc((&wq.x)[m]);
                #pragma unroll
                for (int xo = 0; xo < XPT; ++xo)
                    acc[s][xo] = wv * p[xo + j] + acc[s][xo];
            }
        }
        {   // f = 48 -> i=6, j=6 (b32 read, 2-way bank alias: free)
            const half2_t wv = bc(wp[48]);
            #pragma unroll
            for (int xo = 0; xo < XPT; ++xo)
                acc[0][xo] = wv * p[xo + 6] + acc[0][xo];
        }

        const int y = yi - 3;
        if (y >= y0) {                       // upper bound guaranteed by loop end
            float* orow = ob + ((size_t)y * WW + x0) * CC + c0;
            #pragma unroll
            for (int xo = 0; xo < XPT; ++xo) {
                float2 ov = { (float)acc[0][xo].x, (float)acc[0][xo].y };
                *(float2*)(orow + xo * CC) = ov;
            }
        }

        // Shift ring, open fresh top slot.
        #pragma unroll
        for (int s = 0; s < KH - 1; ++s)
            #pragma unroll
            for (int xo = 0; xo < XPT; ++xo) acc[s][xo] = acc[s + 1][xo];
        #pragma unroll
        for (int xo = 0; xo < XPT; ++xo) acc[KH - 1][xo] = half2_t{0, 0};

        // Pack next row's taps (~2 passes after their issue).
        #pragma unroll
        for (int j = 0; j < NTAP; ++j) p[j] = pk(tsrc[j].x, tsrc[j].y);
    };

    #pragma unroll 1
    for (int pp = 0; pp < NPASS / 2; ++pp) {
        const int r = yi0 + 2 * pp;
        issue_taps(tA, r + 2);    // depth-2: consumed at end of pass(r+1)
        pass(r, tB);
        issue_taps(tB, r + 3);
        pass(r + 1, tA);
    }
}

extern "C" void kernel_launch(void* const* d_in, const int* in_sizes, int n_in,
                              void* d_out, int out_size, void* d_ws, size_t ws_size,
                              hipStream_t stream) {
    const float* in  = (const float*)d_in[0];
    const float* ker = (const float*)d_in[1];
    float*       out = (float*)d_out;

    crossconv_kernel<<<GRID, 256, 0, stream>>>(in, ker, out);
}

// Round 19
// 143.341 us; speedup vs baseline: 3.2085x; 3.2085x over previous
//
#include <hip/hip_runtime.h>

// Per-sample depthwise 7x7 cross-correlation, NHWC, SAME padding.
// inputs:  [B,H,W,C] fp32, kernels: [B,7,7,C] fp32, out: [B,H,W,C] fp32.
// out[b,y,x,c] = sum_{i,j} in[b, y+i-3, x+j-3, c] * ker[b,i,j,c]  (zero pad)
//
// R19 = R18 (c-pair layout, depth-2 A/B tap prefetch, fp16 pk_fma accum)
// with PLAIN __launch_bounds__(256) — no min-waves hint. Session evidence:
// explicit occupancy hints (R2/R6/R18) make the allocator SNAP to the tier
// boundary and spill; plain bounds (R9) let demand float (108 regs, no
// spill). Demand here ~95-110 regs -> ~4 waves/SIMD = exactly the 16
// waves/CU the 1024-block grid needs. This unlocks what the 64-reg iron law
// blocked all session: deep prefetch + efficient engine + full residency.

#define BB 32
#define HH 128
#define WW 128
#define CC 128
#define KH 7
#define KW 7

#define XPT 4                        // x outputs per thread
#define NTAP (XPT + KW - 1)          // 10 tap columns per thread
#define XG 4                         // x-groups (waves) per 256-thr block
#define SLABW (XG * XPT)             // 16 output columns per block
#define NXS (WW / SLABW)             // 8 x-slabs
#define YSPLIT 4
#define YROWS (HH / YSPLIT)          // 32 output rows per block
#define GRID (BB * NXS * YSPLIT)     // 1024 blocks = 4/CU, 16 waves/CU
#define WSTRIDE 52                   // per-c-pair weight uints (49 + pad)
#define NPASS (YROWS + KH - 1)       // 38 passes = 19 A/B pairs

typedef _Float16 half2_t __attribute__((ext_vector_type(2)));

static __device__ __forceinline__ half2_t pk(float a, float b) {
#if __has_builtin(__builtin_amdgcn_cvt_pkrtz)
    return __builtin_bit_cast(half2_t, __builtin_amdgcn_cvt_pkrtz(a, b));
#else
    half2_t r; r.x = (_Float16)a; r.y = (_Float16)b; return r;
#endif
}

static __device__ __forceinline__ half2_t bc(unsigned u) {
    return __builtin_bit_cast(half2_t, u);
}

__global__ __launch_bounds__(256) void crossconv_kernel(
    const float* __restrict__ in,
    const float* __restrict__ ker,
    float* __restrict__ out)
{
    __shared__ unsigned lds_w[64 * WSTRIDE];   // 13312 B

    const int tid  = threadIdx.x;
    const int lane = tid & 63;        // c-pair index; c0 = 2*lane
    const int c0   = lane * 2;
    const int xg   = __builtin_amdgcn_readfirstlane(tid >> 6);  // 0..3, per-wave

    // Bijective XCD swizzle (GRID=1024, 128 blocks/XCD = 4 whole samples).
    const int bid = blockIdx.x;
    const int swz = (bid & 7) * (GRID / 8) + (bid >> 3);
    const int b  = swz >> 5;          // 32 blocks per sample (8 xs x 4 yh)
    const int xs = (swz >> 2) & 7;
    const int yh = swz & 3;
    const int x0 = xs * SLABW + xg * XPT;   // wave-uniform
    const int y0 = yh * YROWS;

    // Stage per-c-pair packed weights: lds_w[pair][f] = (w_f[c0], w_f[c0+1]).
    {
        const float* kb = ker + ((size_t)b * KH * KW) * CC + c0;
        for (int f = xg; f < KH * KW; f += XG) {
            const float2 kv = *(const float2*)(kb + (size_t)f * CC);
            lds_w[lane * WSTRIDE + f] = __builtin_bit_cast(unsigned, pk(kv.x, kv.y));
        }
    }
    __syncthreads();

    const float* ib = in  + ((size_t)b * HH * WW) * CC;
    float*       ob = out + ((size_t)b * HH * WW) * CC;
    const unsigned* wp = &lds_w[lane * WSTRIDE];

    const bool interior = (x0 >= 3) && (x0 + 6 < WW);

    // Issue the 10 float2 tap loads for row yi (consumed ~2 passes later).
    // Base rebased to col x0+2: offsets (j-5)*512 B in [-2560,2048], 13-bit imm.
    auto issue_taps = [&](float2* t, int yi) {
        if (yi < 0 || yi >= HH) {
            #pragma unroll
            for (int j = 0; j < NTAP; ++j) t[j] = float2{0.0f, 0.0f};
            return;
        }
        const float* base = ib + (size_t)yi * WW * CC + (x0 + 2) * CC + c0;
        if (interior) {
            #pragma unroll
            for (int j = 0; j < NTAP; ++j)
                t[j] = *(const float2*)(base + (j - 5) * CC);
        } else {
            #pragma unroll
            for (int j = 0; j < NTAP; ++j) {
                const int xx = x0 - 3 + j;
                t[j] = (xx >= 0 && xx < WW) ? *(const float2*)(base + (j - 5) * CC)
                                            : float2{0.0f, 0.0f};
            }
        }
    };

    // Sliding ring: acc[s][xo] = half2 (c0,c1) partials for output row yi-3+s.
    half2_t acc[KH][XPT];
    #pragma unroll
    for (int s = 0; s < KH; ++s)
        #pragma unroll
        for (int xo = 0; xo < XPT; ++xo) acc[s][xo] = half2_t{0, 0};

    const int yi0 = y0 - 3;

    // Packed current-row taps: p[j] = (t[j].c0, t[j].c1). Output xo uses p[xo+j].
    half2_t p[NTAP];
    float2 tA[NTAP], tB[NTAP];

    issue_taps(tA, yi0);
    #pragma unroll
    for (int j = 0; j < NTAP; ++j) p[j] = pk(tA[j].x, tA[j].y);
    issue_taps(tB, yi0 + 1);

    // One pass: dots for input row yi on p, store completed output row,
    // ring shift, then pack NEXT row from tsrc (vmcnt wait lands there).
    auto pass = [&](int yi, const float2* tsrc) {
        // Prevent LICM of the 49 weight quads (would need +49 regs -> spill).
        asm volatile("" ::: "memory");

        #pragma unroll
        for (int k = 0; k < 12; ++k) {
            const uint4 wq = *(const uint4*)(wp + k * 4);
            #pragma unroll
            for (int m = 0; m < 4; ++m) {
                const int f = k * 4 + m;
                const int i = f / KW, j = f % KW;
                const int s = 6 - i;
                const half2_t wv = bc((&wq.x)[m]);
                #pragma unroll
                for (int xo = 0; xo < XPT; ++xo)
                    acc[s][xo] = wv * p[xo + j] + acc[s][xo];
            }
        }
        {   // f = 48 -> i=6, j=6 (b32 read, 2-way bank alias: free)
            const half2_t wv = bc(wp[48]);
            #pragma unroll
            for (int xo = 0; xo < XPT; ++xo)
                acc[0][xo] = wv * p[xo + 6] + acc[0][xo];
        }

        const int y = yi - 3;
        if (y >= y0) {                       // upper bound guaranteed by loop end
            float* orow = ob + ((size_t)y * WW + x0) * CC + c0;
            #pragma unroll
            for (int xo = 0; xo < XPT; ++xo) {
                float2 ov = { (float)acc[0][xo].x, (float)acc[0][xo].y };
                *(float2*)(orow + xo * CC) = ov;
            }
        }

        // Shift ring, open fresh top slot.
        #pragma unroll
        for (int s = 0; s < KH - 1; ++s)
            #pragma unroll
            for (int xo = 0; xo < XPT; ++xo) acc[s][xo] = acc[s + 1][xo];
        #pragma unroll
        for (int xo = 0; xo < XPT; ++xo) acc[KH - 1][xo] = half2_t{0, 0};

        // Pack next row's taps (~2 passes after their issue).
        #pragma unroll
        for (int j = 0; j < NTAP; ++j) p[j] = pk(tsrc[j].x, tsrc[j].y);
    };

    #pragma unroll 1
    for (int pp = 0; pp < NPASS / 2; ++pp) {
        const int r = yi0 + 2 * pp;
        issue_taps(tA, r + 2);    // depth-2: consumed at end of pass(r+1)
        pass(r, tB);
        issue_taps(tB, r + 3);
        pass(r + 1, tA);
    }
}

extern "C" void kernel_launch(void* const* d_in, const int* in_sizes, int n_in,
                              void* d_out, int out_size, void* d_ws, size_t ws_size,
                              hipStream_t stream) {
    const float* in  = (const float*)d_in[0];
    const float* ker = (const float*)d_in[1];
    float*       out = (float*)d_out;

    crossconv_kernel<<<GRID, 256, 0, stream>>>(in, ker, out);
}

// Round 20
// 141.497 us; speedup vs baseline: 3.2503x; 1.0130x over previous
//
#include <hip/hip_runtime.h>

// Per-sample depthwise 7x7 cross-correlation, NHWC, SAME padding.
// inputs:  [B,H,W,C] fp32, kernels: [B,7,7,C] fp32, out: [B,H,W,C] fp32.
// out[b,y,x,c] = sum_{i,j} in[b, y+i-3, x+j-3, c] * ker[b,i,j,c]  (zero pad)
//
// R20 = R16 (best: XPT=8, v_pk_fma_f16 fp16-accum, pre-broadcast weights in
// LDS, 256-thr blocks, GRID=1024) + DEPTH-2 A/B tap prefetch in the 128-reg
// tier. R19 proved plain __launch_bounds__(256) floats the allocator past 64
// spill-free (88 regs), and this grid (16 waves/CU) only needs 4 waves/SIMD
// <= 128 regs -- so the +14 regs for a second tap set are FREE. Issue->use
// distance grows from ~1 pass (~550 cyc) to ~2 passes (~1100 cyc), covering
// the ~900-cyc HBM miss latency R16's depth-1 leaves exposed.
// Everything else is byte-identical to R16's engine.

#define BB 32
#define HH 128
#define WW 128
#define CC 128
#define KH 7
#define KW 7

#define XPT 8                        // x outputs per thread (4 half2 pairs)
#define NTAP (XPT + KW - 1)          // 14 tap columns per thread
#define XG 2                         // x-groups per block (256 threads / 128 c)
#define SLABW (XG * XPT)             // 16 output columns per block
#define NXS (WW / SLABW)             // 8 x-slabs
#define YSPLIT 4
#define YROWS (HH / YSPLIT)          // 32 output rows per block
#define GRID (BB * NXS * YSPLIT)     // 1024 blocks = 4 per CU (16 waves/CU)
#define WSTRIDE 60                   // per-c weight uints (7 rows x 8 + pad)
#define NPASS (YROWS + KH - 1)       // 38 single-row passes = 19 A/B pairs

typedef _Float16 half2_t __attribute__((ext_vector_type(2)));

static __device__ __forceinline__ half2_t pk(float a, float b) {
#if __has_builtin(__builtin_amdgcn_cvt_pkrtz)
    return __builtin_bit_cast(half2_t, __builtin_amdgcn_cvt_pkrtz(a, b));
#else
    half2_t r; r.x = (_Float16)a; r.y = (_Float16)b; return r;
#endif
}

static __device__ __forceinline__ half2_t bc(unsigned u) {
    return __builtin_bit_cast(half2_t, u);
}

__global__ __launch_bounds__(256) void crossconv_kernel(
    const float* __restrict__ in,
    const float* __restrict__ ker,
    float* __restrict__ out)
{
    __shared__ unsigned lds_w[CC * WSTRIDE];   // 30720 B

    const int tid = threadIdx.x;
    const int c  = tid & (CC - 1);   // lanes contiguous in c -> coalesced
    const int xg = __builtin_amdgcn_readfirstlane(tid >> 7);   // 0..1, wave-uniform

    // Bijective XCD swizzle (GRID=1024, 128 blocks/XCD = 4 whole samples).
    const int bid = blockIdx.x;
    const int swz = (bid & 7) * (GRID / 8) + (bid >> 3);
    const int b  = swz >> 5;         // 32 blocks per sample (8 xs x 4 yh)
    const int xs = (swz >> 2) & 7;
    const int yh = swz & 3;
    const int x0 = xs * SLABW + xg * XPT;  // wave-uniform (scalar)
    const int y0 = yh * YROWS;

    // Stage PRE-BROADCAST weights into LDS: f = i*7+j (0..48) ->
    // lds_w[c*60 + i*8 + j] = (w_f, w_f) packed fp16. Quad stride 15 (odd)
    // -> bijective mod 8 -> conflict-free b128 reads.
    {
        const float* kb = ker + ((size_t)b * KH * KW) * CC + c;
        for (int f = xg; f < KH * KW; f += XG) {
            const int i = f / KW, j = f - i * KW;
            const float wv = kb[f * CC];
            lds_w[c * WSTRIDE + i * 8 + j] =
                __builtin_bit_cast(unsigned, pk(wv, wv));
        }
    }
    __syncthreads();

    const float* ib = in  + ((size_t)b * HH * WW) * CC;
    float*       ob = out + ((size_t)b * HH * WW) * CC;
    const unsigned* wp = &lds_w[c * WSTRIDE];

    const bool interior = (x0 >= 3) && (x0 + NTAP - 3 < WW);

    // Issue the 14 tap loads for row yi (consumed ~2 passes later). Base
    // rebased to col x0+2: offsets (j-5)*512 B in [-2560,3584], 13-bit imm.
    auto issue_taps = [&](float* t, int yi) {
        if (yi < 0 || yi >= HH) {
            #pragma unroll
            for (int j = 0; j < NTAP; ++j) t[j] = 0.0f;
            return;
        }
        const float* base = ib + (size_t)yi * WW * CC + (x0 + 2) * CC + c;
        if (interior) {
            #pragma unroll
            for (int j = 0; j < 13; ++j)
                t[j] = base[(j - 5) * CC];                 // imm offsets
            t[13] = (base + 8 * CC)[0];
        } else {
            #pragma unroll
            for (int j = 0; j < NTAP; ++j) {
                const int xx = x0 - 3 + j;
                t[j] = (xx >= 0 && xx < WW) ? base[(j - 5) * CC] : 0.0f;
            }
        }
    };

    // Sliding ring: acc[s][q] = half2 partials for outputs (x0+2q, x0+2q+1)
    // of output row y = yi-3+s.
    half2_t acc[KH][XPT / 2];
    #pragma unroll
    for (int s = 0; s < KH; ++s)
        #pragma unroll
        for (int q = 0; q < XPT / 2; ++q) acc[s][q] = half2_t{0, 0};

    const int yi0 = y0 - 3;

    // Packed tap pairs p[m] = (t[m], t[m+1]), m=0..12:
    // even m=2k from cvt_pkrtz; odd m=2k+1 via alignbit(p[2k+2], p[2k]).
    // Output pair q uses p[2q+j], j=0..6.
    half2_t p[13];
    float tA[NTAP], tB[NTAP];

    auto pack = [&](const float* t) {
        #pragma unroll
        for (int k = 0; k < 7; ++k) p[2 * k] = pk(t[2 * k], t[2 * k + 1]);
        #pragma unroll
        for (int k = 0; k < 6; ++k)
            p[2 * k + 1] = __builtin_bit_cast(half2_t, __builtin_amdgcn_alignbit(
                               __builtin_bit_cast(unsigned, p[2 * k + 2]),
                               __builtin_bit_cast(unsigned, p[2 * k]), 16));
    };

    // Prologue: row yi0 packed immediately (one exposed wait); row yi0+1 in
    // flight in tB.
    issue_taps(tA, yi0);
    pack(tA);
    issue_taps(tB, yi0 + 1);

    // One pass: dots for input row yi on p, store completed output row,
    // ring shift, then pack the NEXT row from tsrc (vmcnt wait lands there,
    // ~2 passes after its issue).
    auto pass = [&](int yi, const float* tsrc) {
        // Keep per-pass LDS weight reads in the loop (hoisting 49 broadcast
        // pairs would overflow even the 128-reg tier).
        asm volatile("" ::: "memory");

        #pragma unroll
        for (int i = 0; i < KH; ++i) {
            const uint4 q0 = *(const uint4*)(wp + i * 8);      // w0..w3 bcast
            const uint4 q1 = *(const uint4*)(wp + i * 8 + 4);  // w4..w6 bcast
            const int s = 6 - i;
            #pragma unroll
            for (int q = 0; q < XPT / 2; ++q) {
                half2_t a = acc[s][q];
                a = bc(q0.x) * p[2 * q + 0] + a;
                a = bc(q0.y) * p[2 * q + 1] + a;
                a = bc(q0.z) * p[2 * q + 2] + a;
                a = bc(q0.w) * p[2 * q + 3] + a;
                a = bc(q1.x) * p[2 * q + 4] + a;
                a = bc(q1.y) * p[2 * q + 5] + a;
                a = bc(q1.z) * p[2 * q + 6] + a;
                acc[s][q] = a;
            }
        }

        const int y = yi - 3;
        if (y >= y0) {                       // upper bound guaranteed by loop end
            float* orow = ob + ((size_t)y * WW + x0) * CC + c;
            #pragma unroll
            for (int q = 0; q < XPT / 2; ++q) {
                orow[(2 * q) * CC]     = (float)acc[0][q].x;
                orow[(2 * q + 1) * CC] = (float)acc[0][q].y;
            }
        }

        // Shift ring, open fresh top slot.
        #pragma unroll
        for (int s = 0; s < KH - 1; ++s)
            #pragma unroll
            for (int q = 0; q < XPT / 2; ++q) acc[s][q] = acc[s + 1][q];
        #pragma unroll
        for (int q = 0; q < XPT / 2; ++q) acc[KH - 1][q] = half2_t{0, 0};

        // Pack the next row's taps.
        pack(tsrc);
    };

    #pragma unroll 1
    for (int pp = 0; pp < NPASS / 2; ++pp) {
        const int r = yi0 + 2 * pp;
        // Depth-2: loads for row r+2 issued now, packed at end of pass(r+1).
        issue_taps(tA, (2 * pp + 2 < NPASS) ? (r + 2) : -1);
        pass(r, tB);
        issue_taps(tB, (2 * pp + 3 < NPASS) ? (r + 3) : -1);
        pass(r + 1, tA);
    }
}

extern "C" void kernel_launch(void* const* d_in, const int* in_sizes, int n_in,
                              void* d_out, int out_size, void* d_ws, size_t ws_size,
                              hipStream_t stream) {
    const float* in  = (const float*)d_in[0];
    const float* ker = (const float*)d_in[1];
    float*       out = (float*)d_out;

    crossconv_kernel<<<GRID, 256, 0, stream>>>(in, ker, out);
}

// Round 21
// 127.520 us; speedup vs baseline: 3.6066x; 1.1096x over previous
//
#include <hip/hip_runtime.h>

// Per-sample depthwise 7x7 cross-correlation, NHWC, SAME padding.
// inputs:  [B,H,W,C] fp32, kernels: [B,7,7,C] fp32, out: [B,H,W,C] fp32.
// out[b,y,x,c] = sum_{i,j} in[b, y+i-3, x+j-3, c] * ker[b,i,j,c]  (zero pad)
//
// FINAL = R16, the session's empirical optimum (128.1 us; 8 structural
// variants at 140-460 us all falsified). Key elements, each A/B-proven:
//  - fp16 v_pk_fma_f16 with fp16 accumulation, XPT=8 (lo/hi = adjacent x):
//    24.5 pk_fma/output + pack/ring/store overhead amortized over 8 outputs.
//  - weights pre-broadcast (w,w) in LDS [c][7 rows][8 slots]; quad stride 15
//    (odd) -> bijective mod 8 -> conflict-free ds_read_b128.
//  - depth-1 tap prefetch (issue at pass start, pack at pass end). Depth-2
//    regressed at BOTH register tiers (R12/R20).
//  - 256-thr blocks, GRID=1024 (4 blocks/CU, 16 waves/CU), bijective XCD
//    swizzle (4 whole samples per XCD's L2).
//  - plain __launch_bounds__ (occupancy hints make the allocator snap to a
//    tier boundary and spill: R2/R6/R18); no multi-pass unroll (R9/R13).

#define BB 32
#define HH 128
#define WW 128
#define CC 128
#define KH 7
#define KW 7

#define XPT 8                        // x outputs per thread (4 half2 pairs)
#define NTAP (XPT + KW - 1)          // 14 tap columns per thread
#define XG 2                         // x-groups per block (256 threads / 128 c)
#define SLABW (XG * XPT)             // 16 output columns per block
#define NXS (WW / SLABW)             // 8 x-slabs
#define YSPLIT 4
#define YROWS (HH / YSPLIT)          // 32 output rows per block
#define GRID (BB * NXS * YSPLIT)     // 1024 blocks = 4 per CU
#define WSTRIDE 60                   // per-c weight uints (7 rows x 8 + pad)
#define NPASS (YROWS + KH - 1)       // 38 single-row passes

typedef _Float16 half2_t __attribute__((ext_vector_type(2)));

static __device__ __forceinline__ half2_t pk(float a, float b) {
#if __has_builtin(__builtin_amdgcn_cvt_pkrtz)
    return __builtin_bit_cast(half2_t, __builtin_amdgcn_cvt_pkrtz(a, b));
#else
    half2_t r; r.x = (_Float16)a; r.y = (_Float16)b; return r;
#endif
}

static __device__ __forceinline__ half2_t bc(unsigned u) {
    return __builtin_bit_cast(half2_t, u);
}

__global__ __launch_bounds__(256) void crossconv_kernel(
    const float* __restrict__ in,
    const float* __restrict__ ker,
    float* __restrict__ out)
{
    __shared__ unsigned lds_w[CC * WSTRIDE];   // 30720 B

    const int tid = threadIdx.x;
    const int c  = tid & (CC - 1);   // lanes contiguous in c -> coalesced
    const int xg = __builtin_amdgcn_readfirstlane(tid >> 7);   // 0..1, wave-uniform

    // Bijective XCD swizzle (GRID=1024, 128 blocks/XCD = 4 whole samples).
    const int bid = blockIdx.x;
    const int swz = (bid & 7) * (GRID / 8) + (bid >> 3);
    const int b  = swz >> 5;         // 32 blocks per sample (8 xs x 4 yh)
    const int xs = (swz >> 2) & 7;
    const int yh = swz & 3;
    const int x0 = xs * SLABW + xg * XPT;  // wave-uniform (scalar)
    const int y0 = yh * YROWS;

    // Stage PRE-BROADCAST weights into LDS: f = i*7+j (0..48) ->
    // lds_w[c*60 + i*8 + j] = (w_f, w_f) packed fp16.
    {
        const float* kb = ker + ((size_t)b * KH * KW) * CC + c;
        for (int f = xg; f < KH * KW; f += XG) {
            const int i = f / KW, j = f - i * KW;
            const float wv = kb[f * CC];
            lds_w[c * WSTRIDE + i * 8 + j] =
                __builtin_bit_cast(unsigned, pk(wv, wv));
        }
    }
    __syncthreads();

    const float* ib = in  + ((size_t)b * HH * WW) * CC;
    float*       ob = out + ((size_t)b * HH * WW) * CC;
    const unsigned* wp = &lds_w[c * WSTRIDE];

    const bool interior = (x0 >= 3) && (x0 + NTAP - 3 < WW);

    // Tap loads rebased to column x0+2: offsets (j-5)*512 B for j=0..12 fall
    // in [-2560, 3584] (13-bit imm); t[13] via a second base.
    auto load_taps = [&](float* t, int yi) {
        if (yi < 0 || yi >= HH) {
            #pragma unroll
            for (int j = 0; j < NTAP; ++j) t[j] = 0.0f;
            return;
        }
        const float* base = ib + (size_t)yi * WW * CC + (x0 + 2) * CC + c;
        if (interior) {
            #pragma unroll
            for (int j = 0; j < 13; ++j)
                t[j] = base[(j - 5) * CC];                 // imm offsets
            t[13] = (base + 8 * CC)[0];
        } else {
            #pragma unroll
            for (int j = 0; j < NTAP; ++j) {
                const int xx = x0 - 3 + j;
                t[j] = (xx >= 0 && xx < WW) ? base[(j - 5) * CC] : 0.0f;
            }
        }
    };

    // Sliding ring: acc[s][q] = half2 partials for outputs (x0+2q, x0+2q+1)
    // of output row y = yi-3+s.
    half2_t acc[KH][XPT / 2];
    #pragma unroll
    for (int s = 0; s < KH; ++s)
        #pragma unroll
        for (int q = 0; q < XPT / 2; ++q) acc[s][q] = half2_t{0, 0};

    const int yi0 = y0 - 3;

    // Packed tap pairs p[m] = (t[m], t[m+1]), m=0..12:
    // even m=2k from cvt_pkrtz; odd m=2k+1 via alignbit(p[2k+2], p[2k]).
    // Output pair q uses p[2q+j], j=0..6.
    float t[NTAP];
    half2_t p[13];
    auto pack = [&]() {
        #pragma unroll
        for (int k = 0; k < 7; ++k) p[2 * k] = pk(t[2 * k], t[2 * k + 1]);
        #pragma unroll
        for (int k = 0; k < 6; ++k)
            p[2 * k + 1] = __builtin_bit_cast(half2_t, __builtin_amdgcn_alignbit(
                               __builtin_bit_cast(unsigned, p[2 * k + 2]),
                               __builtin_bit_cast(unsigned, p[2 * k]), 16));
    };

    load_taps(t, yi0);
    pack();

    #pragma unroll 1
    for (int pp = 0; pp < NPASS; ++pp) {
        const int yi = yi0 + pp;

        // Issue next row's tap loads; the dot pass hides the latency.
        load_taps(t, (pp + 1 < NPASS) ? (yi + 1) : HH);

        // Keep per-pass LDS weight reads in the loop (hoisting 49 broadcast
        // pairs would blow the register budget and spill).
        asm volatile("" ::: "memory");

        #pragma unroll
        for (int i = 0; i < KH; ++i) {
            const uint4 q0 = *(const uint4*)(wp + i * 8);      // w0..w3 bcast
            const uint4 q1 = *(const uint4*)(wp + i * 8 + 4);  // w4..w6 bcast
            const int s = 6 - i;
            #pragma unroll
            for (int q = 0; q < XPT / 2; ++q) {
                half2_t a = acc[s][q];
                a = bc(q0.x) * p[2 * q + 0] + a;
                a = bc(q0.y) * p[2 * q + 1] + a;
                a = bc(q0.z) * p[2 * q + 2] + a;
                a = bc(q0.w) * p[2 * q + 3] + a;
                a = bc(q1.x) * p[2 * q + 4] + a;
                a = bc(q1.y) * p[2 * q + 5] + a;
                a = bc(q1.z) * p[2 * q + 6] + a;
                acc[s][q] = a;
            }
        }

        const int y = yi - 3;
        if (y >= y0) {                       // upper bound guaranteed by loop end
            float* orow = ob + ((size_t)y * WW + x0) * CC + c;
            #pragma unroll
            for (int q = 0; q < XPT / 2; ++q) {
                orow[(2 * q) * CC]     = (float)acc[0][q].x;
                orow[(2 * q + 1) * CC] = (float)acc[0][q].y;
            }
        }

        // Shift ring, open fresh top slot.
        #pragma unroll
        for (int s = 0; s < KH - 1; ++s)
            #pragma unroll
            for (int q = 0; q < XPT / 2; ++q) acc[s][q] = acc[s + 1][q];
        #pragma unroll
        for (int q = 0; q < XPT / 2; ++q) acc[KH - 1][q] = half2_t{0, 0};

        // Pack the prefetched row for the next pass.
        pack();
    }
}

extern "C" void kernel_launch(void* const* d_in, const int* in_sizes, int n_in,
                              void* d_out, int out_size, void* d_ws, size_t ws_size,
                              hipStream_t stream) {
    const float* in  = (const float*)d_in[0];
    const float* ker = (const float*)d_in[1];
    float*       out = (float*)d_out;

    crossconv_kernel<<<GRID, 256, 0, stream>>>(in, ker, out);
}